// Round 7
// baseline (112.662 us; speedup 1.0000x reference)
//
#include <hip/hip_runtime.h>
#include <hip/hip_bf16.h>

// Problem constants (fixed by reference setup_inputs)
#define I_DIM  7168
#define O_DIM  18432
#define SW     56      // I_DIM/128 (scale row stride)
#define BN     128     // O rows per block tile (= exactly one scale block)
#define BK     128     // K floats per tile: 512B per row visit (DRAM page efficiency)
#define ROWS   160     // 128 W rows + 32 x rows staged per tile
#define NTO    144     // O_DIM/BN
#define KC     8       // split-K
#define KCHUNK 896     // I_DIM/KC = 7 scale blocks = 7 tiles
#define NTILES 7       // KCHUNK/BK

typedef float  f32x4  __attribute__((ext_vector_type(4)));
typedef float  f32x16 __attribute__((ext_vector_type(16)));
typedef __bf16 bf16x8 __attribute__((ext_vector_type(8)));
typedef __bf16 bf16x4 __attribute__((ext_vector_type(4)));

__global__ __launch_bounds__(256, 2) void fp8lin_gemm(
    const float* __restrict__ x,      // [32, 7168]
    const float* __restrict__ w,      // [18432, 7168]
    const float* __restrict__ s,      // [144, 56]
    float* __restrict__ out) {        // [32, 18432], pre-zeroed
  // Two staging buffers: [ROWS][BK] bf16 (256B rows), swizzle byte ^= (row&15)<<4
  // -> ds_read_b128 at fixed col across 32 rows is fully conflict-free.
  __shared__ __bf16 lds[2][ROWS * BK];   // 2 x 40 KiB = 80 KiB -> 2 blocks/CU

  const int tid  = threadIdx.x;
  const int wid  = tid >> 6;
  const int lane = tid & 63;
  const int r    = lane & 31;       // MFMA row/col index
  const int g    = lane >> 5;       // k-group

  const int bid = blockIdx.x;
  const int ot  = bid % NTO;        // consecutive blocks -> consecutive O tiles
  const int kc  = bid / NTO;
  const int o0  = ot * BN;
  const int k0b = kc * KCHUNK;

  // Staging coords: round j covers rows j*8..j*8+7; 32 threads cover one full
  // 512B row -> per wave instruction: 2 rows x 512B contiguous (16 full lines).
  const int srow = tid >> 5;          // 0..7
  const int scol = (tid & 31) * 4;    // float col within BK (0..124)

  f32x4 L[20];   // held global loads (80 VGPRs), static-indexed only

  auto issue = [&](int t) {
    const int kk = k0b + t * BK;
#pragma unroll
    for (int j = 0; j < 20; ++j) {
      const int row = j * 8 + srow;   // 0..159
      const float* p = (j < 16)
          ? (w + (size_t)(o0 + row) * I_DIM + kk + scol)     // W rows 0..127
          : (x + (size_t)(row - 128) * I_DIM + kk + scol);   // x rows 128..159
      L[j] = *reinterpret_cast<const f32x4*>(p);
    }
  };

  auto writeb = [&](int buf, float sc) {
    char* base = (char*)&lds[buf][0];
#pragma unroll
    for (int j = 0; j < 20; ++j) {
      const int row = j * 8 + srow;
      const float scale = (j < 16) ? sc : 1.0f;   // x rows unscaled
      bf16x4 v;
      v[0] = (__bf16)(L[j][0] * scale);
      v[1] = (__bf16)(L[j][1] * scale);
      v[2] = (__bf16)(L[j][2] * scale);
      v[3] = (__bf16)(L[j][3] * scale);
      int byte = row * (BK * 2) + scol * 2;      // [row][col] bf16, 256 B rows
      byte ^= ((row & 15) << 4);                 // T2 swizzle (write side)
      *reinterpret_cast<bf16x4*>(base + byte) = v;
    }
  };

  f32x16 acc;
#pragma unroll
  for (int i = 0; i < 16; ++i) acc[i] = 0.0f;

  const int xrow = 128 + r;          // x staged at tile rows 128..159
  const int wrow = wid * 32 + r;     // this wave's 32 W rows
  const int xswz = (xrow & 15) << 4;
  const int wswz = (wrow & 15) << 4;

  auto compute = [&](int buf) {
    const char* base = (const char*)&lds[buf][0];
#pragma unroll
    for (int kb = 0; kb < BK; kb += 16) {
      const int cb = kb * 2 + g * 16;
      bf16x8 a = *reinterpret_cast<const bf16x8*>(base + ((xrow * 256 + cb) ^ xswz));
      bf16x8 b = *reinterpret_cast<const bf16x8*>(base + ((wrow * 256 + cb) ^ wswz));
      acc = __builtin_amdgcn_mfma_f32_32x32x16_bf16(a, b, acc, 0, 0, 0);
    }
  };

  issue(0);
  for (int t = 0; t < NTILES; ++t) {
    const float sc = s[ot * SW + ((k0b + t * BK) >> 7)];  // block-uniform
    const int buf = t & 1;
    writeb(buf, sc);
    if (t + 1 < NTILES) issue(t + 1);   // prefetch stays in flight across barrier
    asm volatile("s_waitcnt lgkmcnt(0)" ::: "memory");  // ds_writes visible
    __builtin_amdgcn_s_barrier();                        // raw: no vmcnt drain
    __builtin_amdgcn_sched_barrier(0);                   // pin ds_reads below
    compute(buf);
    // One barrier/tile suffices: barrier[t] + lgkmcnt(0) transitively separates
    // compute(buf)[t-1] reads from write(buf)[t+1] writes.
  }

  // C/D layout (32x32, verified m74/m101): col=lane&31, row=(reg&3)+8*(reg>>2)+4*g
  float* op = out + o0 + wid * 32 + r;
#pragma unroll
  for (int reg = 0; reg < 16; ++reg) {
    const int row = (reg & 3) + 8 * (reg >> 2) + 4 * g;
    __hip_atomic_fetch_add(op + (size_t)row * O_DIM, acc[reg],
                           __ATOMIC_RELAXED, __HIP_MEMORY_SCOPE_AGENT);
  }
}

extern "C" void kernel_launch(void* const* d_in, const int* in_sizes, int n_in,
                              void* d_out, int out_size, void* d_ws, size_t ws_size,
                              hipStream_t stream) {
  const float* x = (const float*)d_in[0];
  const float* w = (const float*)d_in[1];
  const float* s = (const float*)d_in[2];
  float* out = (float*)d_out;

  // Split-K accumulates with atomics; output must start at zero every call.
  (void)hipMemsetAsync(out, 0, (size_t)out_size * sizeof(float), stream);

  dim3 grid(NTO * KC);   // 1152 blocks @ 2 blocks/CU resident
  dim3 block(256);       // 4 waves
  fp8lin_gemm<<<grid, block, 0, stream>>>(x, w, s, out);
}

// Round 8
// 97.760 us; speedup vs baseline: 1.1524x; 1.1524x over previous
//
#include <hip/hip_runtime.h>
#include <hip/hip_bf16.h>

// Problem constants (fixed by reference setup_inputs)
#define I_DIM  7168
#define O_DIM  18432
#define SW     56      // I_DIM/128 (scale row stride)
#define BN     128     // O rows per block tile (= exactly one scale block)
#define BK     64      // K floats per tile (never straddles a 128-scale block)
#define ROWS   160     // 128 W rows + 32 x rows staged per tile
#define NTO    144     // O_DIM/BN
#define KC     8       // split-K
#define KCHUNK 896     // I_DIM/KC = 7 scale blocks exactly
#define NTILES 14      // KCHUNK/BK (even: clean 2x unroll)

typedef float  f32x4  __attribute__((ext_vector_type(4)));
typedef float  f32x16 __attribute__((ext_vector_type(16)));
typedef __bf16 bf16x8 __attribute__((ext_vector_type(8)));
typedef __bf16 bf16x4 __attribute__((ext_vector_type(4)));

__global__ __launch_bounds__(256, 3) void fp8lin_gemm(
    const float* __restrict__ x,      // [32, 7168]
    const float* __restrict__ w,      // [18432, 7168]
    const float* __restrict__ s,      // [144, 56]
    float* __restrict__ out) {        // [32, 18432], pre-zeroed
  // Two staging buffers: [ROWS][BK] bf16, XOR-swizzled (byte ^= (row&7)<<4).
  __shared__ __bf16 lds[2][ROWS * BK];   // 2 x 20 KiB = 40 KiB

  const int tid  = threadIdx.x;
  const int wid  = tid >> 6;
  const int lane = tid & 63;
  const int r    = lane & 31;       // MFMA row/col index
  const int g    = lane >> 5;       // k-group

  const int bid = blockIdx.x;
  const int ot  = bid % NTO;        // consecutive blocks -> consecutive O tiles
  const int kc  = bid / NTO;
  const int o0  = ot * BN;
  const int k0b = kc * KCHUNK;

  // Staging coords: thread t covers row j*16 + (t>>4), float col (t&15)*4
  // -> each wave instr reads 1 KB contiguous (16 fully-used lines).
  const int srow = tid >> 4;          // 0..15
  const int scol = (tid & 15) * 4;    // float col within BK

  // T14: double-buffered staging registers — issue(t+1) has no WAR on
  // writeb(t)'s source; >=10 loads/wave stay in flight across the barrier.
  f32x4 LA[10], LB[10];

  auto issue = [&](f32x4 (&L)[10], int t) {
    const int kk = k0b + t * BK;
#pragma unroll
    for (int j = 0; j < 10; ++j) {
      const int row = j * 16 + srow;   // 0..159
      if (j < 8) {
        // W is read exactly once: nontemporal (nt) -> don't churn L2/L3,
        // protect the hot x / out lines from eviction.
        const float* p = w + (size_t)(o0 + row) * I_DIM + kk + scol;
        L[j] = __builtin_nontemporal_load(reinterpret_cast<const f32x4*>(p));
      } else {
        // x is hot (re-read by every block): keep it cached.
        const float* p = x + (size_t)(row - 128) * I_DIM + kk + scol;
        L[j] = *reinterpret_cast<const f32x4*>(p);
      }
    }
  };

  auto writeb = [&](const f32x4 (&L)[10], int buf, float sc) {
    char* base = (char*)&lds[buf][0];
#pragma unroll
    for (int j = 0; j < 10; ++j) {
      const int row = j * 16 + srow;
      const float scale = (j < 8) ? sc : 1.0f;   // x rows unscaled
      bf16x4 v;
      v[0] = (__bf16)(L[j][0] * scale);
      v[1] = (__bf16)(L[j][1] * scale);
      v[2] = (__bf16)(L[j][2] * scale);
      v[3] = (__bf16)(L[j][3] * scale);
      int byte = row * (BK * 2) + scol * 2;      // [row][col] bf16, 128 B rows
      byte ^= ((row & 7) << 4);                  // T2 swizzle (write side)
      *reinterpret_cast<bf16x4*>(base + byte) = v;
    }
  };

  f32x16 acc;
#pragma unroll
  for (int i = 0; i < 16; ++i) acc[i] = 0.0f;

  const int xrow = 128 + r;          // x staged at tile rows 128..159
  const int wrow = wid * 32 + r;     // this wave's 32 W rows
  const int xswz = (xrow & 7) << 4;
  const int wswz = (wrow & 7) << 4;

  auto compute = [&](int buf) {
    const char* base = (const char*)&lds[buf][0];
#pragma unroll
    for (int kb = 0; kb < BK; kb += 16) {
      const int cb = kb * 2 + g * 16;
      bf16x8 a = *reinterpret_cast<const bf16x8*>(base + ((xrow * 128 + cb) ^ xswz));
      bf16x8 b = *reinterpret_cast<const bf16x8*>(base + ((wrow * 128 + cb) ^ wswz));
      acc = __builtin_amdgcn_mfma_f32_32x32x16_bf16(a, b, acc, 0, 0, 0);
    }
  };

  const float* srow_p = s + ot * SW;

  issue(LA, 0);
  for (int t = 0; t < NTILES; t += 2) {
    // even tile t -> buf 0, staged in LA
    issue(LB, t + 1);                               // issue-early (t+1<=13 always)
    writeb(LA, 0, srow_p[(k0b + t * BK) >> 7]);     // write-late: LA is a tile old
    asm volatile("s_waitcnt lgkmcnt(0)" ::: "memory");
    __builtin_amdgcn_s_barrier();                   // raw: no vmcnt drain
    __builtin_amdgcn_sched_barrier(0);
    compute(0);

    // odd tile t+1 -> buf 1, staged in LB
    if (t + 2 < NTILES) issue(LA, t + 2);
    writeb(LB, 1, srow_p[(k0b + (t + 1) * BK) >> 7]);
    asm volatile("s_waitcnt lgkmcnt(0)" ::: "memory");
    __builtin_amdgcn_s_barrier();
    __builtin_amdgcn_sched_barrier(0);
    compute(1);
  }

  // C/D layout (32x32, verified m74/m101): col=lane&31, row=(reg&3)+8*(reg>>2)+4*g
  float* op = out + o0 + wid * 32 + r;
#pragma unroll
  for (int reg = 0; reg < 16; ++reg) {
    const int row = (reg & 3) + 8 * (reg >> 2) + 4 * g;
    __hip_atomic_fetch_add(op + (size_t)row * O_DIM, acc[reg],
                           __ATOMIC_RELAXED, __HIP_MEMORY_SCOPE_AGENT);
  }
}

extern "C" void kernel_launch(void* const* d_in, const int* in_sizes, int n_in,
                              void* d_out, int out_size, void* d_ws, size_t ws_size,
                              hipStream_t stream) {
  const float* x = (const float*)d_in[0];
  const float* w = (const float*)d_in[1];
  const float* s = (const float*)d_in[2];
  float* out = (float*)d_out;

  // Split-K accumulates with atomics; output must start at zero every call.
  (void)hipMemsetAsync(out, 0, (size_t)out_size * sizeof(float), stream);

  dim3 grid(NTO * KC);   // 1152 blocks
  dim3 block(256);       // 4 waves
  fp8lin_gemm<<<grid, block, 0, stream>>>(x, w, s, out);
}